// Round 4
// baseline (194.193 us; speedup 1.0000x reference)
//
#include <hip/hip_runtime.h>
#include <hip/hip_bf16.h>
#include <cstdint>

#define QLEN   1024
#define KLEN   2048
#define DMODEL 2048
#define BATCH  4
#define FLEN   (KLEN - QLEN + 1)   // 1025

typedef __bf16 bf16x8 __attribute__((ext_vector_type(8)));
typedef float  f32x4  __attribute__((ext_vector_type(4)));

// Static device scratch — FALLBACK ONLY. Round-3 measured: moving these to the
// harness workspace (hipMalloc-interleaved) cut prep 64->53 us. Keep ws path.
__device__ __align__(16) __bf16 g_ft[(size_t)QLEN * KLEN];           // 4 MiB
__device__ __align__(16) __bf16 g_yt[(size_t)BATCH * DMODEL * KLEN]; // 32 MiB

typedef __attribute__((address_space(1))) void gvoid;
typedef __attribute__((address_space(3))) void svoid;

__device__ __forceinline__ void async_load16(const void* g, void* lds) {
  gvoid* gp = (gvoid*)(uintptr_t)g;
  svoid* sp = (svoid*)(uint32_t)(uintptr_t)lds;   // flat LDS addr low 32 bits == LDS offset
  __builtin_amdgcn_global_load_lds(gp, sp, 16, 0, 0);
}

// ---------------- prep: y^T (blocked+permuted) + FT generation ----------------
// Round-4 theory: VGPR_Count=24 across ALL prior variants proves the allocator
// folds the 16-load stream into a tiny working set (MLP~2-4), capping BW at
// ~2 TB/s. Structural fix: float4 loads (1 KB/wave/instr, 4x fewer loads) and
// a sched_barrier(0) fence between the load block and compute block — all 16
// loads (64 data VGPRs) must be live across it, so serialization is impossible.
//
// yt layout (per batch), permuted so each store is a contiguous 1 KB wave store
// even though lane l holds d-columns {4l..4l+3}:
//   yt[b][mt][g][j][q][i]  where d = g*256 + q*4 + j, m = mt*8 + i
//   linear: b*4194304 + mt*16384 + g*2048 + j*512 + q*8 + i
#define YT_UNITS (BATCH * (KLEN / 8) * (DMODEL / 256))  // 8192 wave-units
#define FT_UNITS ((QLEN * KLEN) / 512)                  // 4096 wave-units
#define PREP_BLOCKS 1024                                // 4096 waves * 3 units exactly

__global__ __launch_bounds__(256) void prep_kernel(const float* __restrict__ x,
                                                   const float* __restrict__ p,
                                                   const int* __restrict__ addp,
                                                   __bf16* __restrict__ ftp,
                                                   __bf16* __restrict__ ytp) {
  __bf16* ft = ftp ? ftp : g_ft;
  __bf16* yt = ytp ? ytp : g_yt;
  const int lane  = threadIdx.x & 63;
  const int gw    = (blockIdx.x * 256 + threadIdx.x) >> 6;  // global wave id
  const int nw    = gridDim.x * 4;                          // 4096 waves
  const float addf = (*addp) ? 1.0f : 0.0f;

  for (int u = gw; u < YT_UNITS + FT_UNITS; u += nw) {
    if (u < YT_UNITS) {
      // unit -> (b, mt, 256-wide d-group); lane owns 4 d columns, 8 m rows.
      const int b  = u >> 11;          // 2048 units per batch (256 mt * 8 g)
      const int r  = u & 2047;
      const int mt = r >> 3;
      const int g  = r & 7;
      const f32x4* xp4 = (const f32x4*)(x + ((size_t)b * KLEN + mt * 8) * DMODEL + g * 256 + 4 * lane);
      const f32x4* pp4 = (const f32x4*)(p + ((size_t)b * KLEN + mt * 8) * DMODEL + g * 256 + 4 * lane);
      f32x4 vx[8], vp[8];
#pragma unroll
      for (int i = 0; i < 8; ++i) vx[i] = xp4[(size_t)i * (DMODEL / 4)];  // 1 KB/instr
#pragma unroll
      for (int i = 0; i < 8; ++i) vp[i] = pp4[(size_t)i * (DMODEL / 4)];
      // Fence: nothing below may be hoisted above, no load may sink below ->
      // all 16 dwordx4 loads issue as one burst with 64 live data VGPRs.
      __builtin_amdgcn_sched_barrier(0);
      __bf16* op = yt + (size_t)b * (size_t)(DMODEL * KLEN) + mt * 16384 + g * 2048 + lane * 8;
#pragma unroll
      for (int j = 0; j < 4; ++j) {
        bf16x8 o;
#pragma unroll
        for (int i = 0; i < 8; ++i) o[i] = (__bf16)(vx[i][j] + addf * vp[i][j]);
        *(bf16x8*)(op + j * 512) = o;   // 64 lanes * 16 B contiguous = 1 KB
      }
    } else {
      // FT[l,m] = cos(2*pi*((l*(m-l)) % 1025)/1025)/sqrt(1025*2048) in band.
      const int uu = (u - YT_UNITS) * 64 + lane;   // [0, QLEN*KLEN/8)
      const int l  = uu >> 8;                      // KLEN/8 = 256 chunks per row
      const int m0 = (uu & 255) * 8;
      const int j0 = m0 - l;
      bf16x8 o = {};
      if (j0 + 7 >= 0 && j0 < FLEN) {
        const float w     = 6.283185307179586f / (float)FLEN;
        const float scale = 1.0f / sqrtf((float)FLEN * (float)KLEN);
#pragma unroll
        for (int i = 0; i < 8; ++i) {
          const int j = j0 + i;
          float vv = 0.0f;
          if (j >= 0 && j < FLEN) {
            const int rr = (l * j) % FLEN;         // exact: l*j < 2^20, magic-mul mod
            vv = cosf((float)rr * w) * scale;
          }
          o[i] = (__bf16)vv;
        }
      }
      *(bf16x8*)(ft + (size_t)uu * 8) = o;
    }
  }
}

// ---------------- GEMM: out[b][l][d] = sum_m FT[l][m] * y[m][d] ----------------
#define BM 128
#define BN 128
#define BK 64

__global__ __launch_bounds__(256) void gemm_kernel(float* __restrict__ out,
                                                   const __bf16* __restrict__ ftq,
                                                   const __bf16* __restrict__ ytq) {
  // grid: (DMODEL/BN, QLEN/BM, BATCH); 4 waves; wave tile 64x64 (4x4 of 16x16x32 MFMA)
  __shared__ __align__(16) __bf16 As[BM * BK];   // [l'][k'] chunk-swizzled, 16 KB
  __shared__ __align__(16) __bf16 Bs[BN * BK];   // chunk-major: chunk (c8, d') at idx c8*128+d', 16 KB
  const int bn = blockIdx.x, bm = blockIdx.y, b = blockIdx.z;
  const int l0 = bm * BM, d0 = bn * BN;
  const int tid  = threadIdx.x;
  const int lane = tid & 63;
  const int wave = tid >> 6;
  const int wr = wave >> 1, wc = wave & 1;
  const int col = lane & 15, quad = lane >> 4;

  f32x4 acc[4][4] = {};

  // band: FT[l,m] nonzero only for l <= m <= l+1024 -> K-tiles [l0/64, (l0+1151)/64]
  const int t0 = l0 >> 6;
  const int t1 = (l0 + BM - 1 + FLEN - 1) >> 6;   // inclusive; 18 tiles
  const __bf16* ftp = ftq ? ftq : g_ft;
  const __bf16* ytp = (ytq ? ytq : g_yt) + (size_t)b * DMODEL * KLEN;  // permuted-blocked

  for (int t = t0; t <= t1; ++t) {
    const int k0 = t * BK;
    // Stage A (FT): 128 rows x 64 k row-major, XOR swizzle on the GLOBAL side
    // (LDS linear; global_load_lds writes lane i at base + i*16).
#pragma unroll
    for (int s = 0; s < 4; ++s) {
      const int cb  = wave * 256 + s * 64;
      const int lc  = cb + lane;
      const int row = lc >> 3;
      const int gc8 = (lc & 7) ^ (row & 7);
      async_load16(ftp + (size_t)(l0 + row) * KLEN + k0 + gc8 * 8, As + cb * 8);
    }
    // Stage B from permuted-blocked yt: chunk (c, dd) for d = d0+dd lives at
    //   mtg*16384 + g*2048 + (dd&3)*512 + (32*(bn&1) + (dd>>2))*8,
    // with mtg = t*8+c, g = bn>>1. LDS dest layout unchanged (chunk-major).
    // Per instr: 4 x 256 B contiguous source segments — coalesced.
#pragma unroll
    for (int s = 0; s < 4; ++s) {
      const int idx = wave * 256 + s * 64 + lane;   // 0..1023
      const int c   = idx >> 7;                     // k-chunk 0..7
      const int dd  = idx & 127;
      const int mtg = t * 8 + c;
      const size_t src = (size_t)mtg * 16384 + (bn >> 1) * 2048
                       + (dd & 3) * 512 + (((bn & 1) << 5) + (dd >> 2)) * 8;
      async_load16(ytp + src, Bs + (size_t)idx * 8);
    }
    __syncthreads();   // drains vmcnt -> staged data visible

#pragma unroll
    for (int kk = 0; kk < 2; ++kk) {
      bf16x8 af[4], bq[4];
      const int c8 = kk * 4 + quad;
#pragma unroll
      for (int ti = 0; ti < 4; ++ti) {
        const int r = wr * 64 + ti * 16 + col;            // A row (l), frag m = lane&15
        af[ti] = *(const bf16x8*)(As + (size_t)((r << 3) + (c8 ^ (r & 7))) * 8);
      }
#pragma unroll
      for (int tj = 0; tj < 4; ++tj) {
        const int r = wc * 64 + tj * 16 + col;            // B row (d), frag n = lane&15
        bq[tj] = *(const bf16x8*)(Bs + (size_t)((c8 << 7) + r) * 8);
      }
#pragma unroll
      for (int ti = 0; ti < 4; ++ti)
#pragma unroll
        for (int tj = 0; tj < 4; ++tj)
          acc[ti][tj] = __builtin_amdgcn_mfma_f32_16x16x32_bf16(af[ti], bq[tj], acc[ti][tj], 0, 0, 0);
    }
    __syncthreads();   // protect LDS from next iteration's staging
  }

  // Epilogue: C/D layout col = lane&15, row = quad*4 + reg  [m89/m91 verified]
#pragma unroll
  for (int ti = 0; ti < 4; ++ti) {
    const int l = l0 + wr * 64 + ti * 16 + quad * 4;
#pragma unroll
    for (int tj = 0; tj < 4; ++tj) {
      const int d = d0 + wc * 64 + tj * 16 + col;
      float* op = out + (size_t)b * QLEN * DMODEL + (size_t)l * DMODEL + d;
#pragma unroll
      for (int r2 = 0; r2 < 4; ++r2) op[(size_t)r2 * DMODEL] = acc[ti][tj][r2];
    }
  }
}

extern "C" void kernel_launch(void* const* d_in, const int* in_sizes, int n_in,
                              void* d_out, int out_size, void* d_ws, size_t ws_size,
                              hipStream_t stream) {
  const float* x   = (const float*)d_in[0];
  const float* p   = (const float*)d_in[1];
  const int* addp  = (const int*)d_in[3];   // add_position (qlen fixed at 1024 by shapes)
  float* out = (float*)d_out;

  // Workspace placement (round-3 measured win): ft/yt in properly interleaved
  // hipMalloc memory. Both arrays fully rewritten every launch before any read,
  // so ws re-poisoning is safe.
  const size_t FT_BYTES = (size_t)QLEN * KLEN * sizeof(__bf16);            // 4 MiB
  const size_t YT_BYTES = (size_t)BATCH * DMODEL * KLEN * sizeof(__bf16);  // 32 MiB
  __bf16* ft = nullptr;
  __bf16* yt = nullptr;
  char* ws = (char*)d_ws;
  if (ws && ws_size >= FT_BYTES + YT_BYTES) {
    ft = (__bf16*)ws;
    yt = (__bf16*)(ws + FT_BYTES);
  } else if (ws && ws_size >= YT_BYTES) {
    yt = (__bf16*)ws;           // prioritize the hot 32 MiB array
  }

  prep_kernel<<<dim3(PREP_BLOCKS), dim3(256), 0, stream>>>(x, p, addp, ft, yt);
  gemm_kernel<<<dim3(DMODEL / BN, QLEN / BM, BATCH), dim3(256), 0, stream>>>(out, ft, yt);
}